// Round 7
// baseline (515.224 us; speedup 1.0000x reference)
//
#include <hip/hip_runtime.h>
#include <hip/hip_bf16.h>

#define DWT_LEN_C 84
#define TDIM 64
#define INNER 4096   // 64 * 8 * 8
#define KOUT 16
#define KSPLIT 8
#define QCOLS 512    // K-chunk width per block (INNER / KSPLIT)
#define STEPS 16     // QCOLS / 32

typedef __attribute__((ext_vector_type(8))) short short8;
typedef __attribute__((ext_vector_type(4))) float floatx4;

__device__ __forceinline__ unsigned short bf16_rne(float f) {
    unsigned u = __float_as_uint(f);
    unsigned r = u + 0x7fffu + ((u >> 16) & 1u);
    return (unsigned short)(r >> 16);
}

// db4 analysis filters
__device__ const float c_dec_lo[8] = {-0.010597401784997278f, 0.032883011666982945f, 0.030841381835986965f,
                                      -0.18703481171888114f, -0.02798376941698385f, 0.6308807679295904f,
                                      0.7148465705525415f, 0.23037781330885523f};
__device__ const float c_dec_hi[8] = {-0.23037781330885523f, 0.7148465705525415f, -0.6308807679295904f,
                                      -0.02798376941698385f, 0.18703481171888114f, 0.030841381835986965f,
                                      -0.032883011666982945f, -0.010597401784997278f};

// Single-level analysis filter bank (reflect pad; left pad 6 for our sizes).
__device__ void afb1d_col(const float* v, int N, float* lo, float* hi, int M) {
    for (int i = 0; i < M; ++i) {
        float slo = 0.f, shi = 0.f;
        for (int j = 0; j < 8; ++j) {
            int idx = 2 * i + j - 6;
            if (idx < 0) idx = -idx;                  // reflect (exclude edge)
            if (idx >= N) idx = 2 * N - 2 - idx;
            float c = v[idx];
            slo = fmaf(c, c_dec_lo[7 - j], slo);      // conv = corr with reversed filter
            shi = fmaf(c, c_dec_hi[7 - j], shi);
        }
        lo[i] = slo; hi[i] = shi;
    }
}

// Fused setup: rebuild W_dwt[84][64] in LDS, emit W_eff bf16 [KOUT][INNER],
// and (block 0) zero the per-rowgroup arrival counters for this run.
__global__ __launch_bounds__(256) void build_weff_bf16(const float* __restrict__ conv_w,
                                                       unsigned short* __restrict__ Wb,
                                                       int* __restrict__ counters, int ngroups) {
    if (blockIdx.x == 0 && (int)threadIdx.x < ngroups) counters[threadIdx.x] = 0;

    __shared__ float Wd[DWT_LEN_C][TDIM];
    const int t0 = threadIdx.x;
    if (t0 < TDIM) {
        float v[64];
        for (int n = 0; n < 64; ++n) v[n] = (n == t0) ? 1.f : 0.f;
        float lo1[35], hi1[35], lo2[21], hi2[21], lo3[14], hi3[14];
        afb1d_col(v, 64, lo1, hi1, 35);
        afb1d_col(lo1, 35, lo2, hi2, 21);
        afb1d_col(lo2, 21, lo3, hi3, 14);
        for (int i = 0; i < 14; ++i) Wd[i][t0] = lo3[i];
        for (int i = 0; i < 35; ++i) Wd[14 + i][t0] = hi1[i];
        for (int i = 0; i < 21; ++i) Wd[49 + i][t0] = hi2[i];
        for (int i = 0; i < 14; ++i) Wd[70 + i][t0] = hi3[i];
    }
    __syncthreads();

    const int idx = blockIdx.x * 256 + threadIdx.x;    // k*4096 + col
    const int k = idx >> 12;
    const int col = idx & 4095;
    const int t = col >> 6;
    const int hw = col & 63;
    float s = 0.f;
    const float* cw = conv_w + (size_t)k * DWT_LEN_C * 64 + hw;
#pragma unroll 4
    for (int dd = 0; dd < DWT_LEN_C; ++dd)
        s = fmaf(cw[dd * 64], Wd[dd][t], s);
    Wb[idx] = bf16_rne(s);
}

// MFMA GEMM: M=B rows, N=16 outputs, K-chunk of 512 cols per block (KSPLIT=8).
// Block: 256 thr / 4 waves, 64 rows (16 per wave). W chunk (16x512 bf16 = 16 KB)
// staged once into LDS, XOR-swizzled for conflict-free ds_read_b128.
// The LAST arriving block of each rowgroup (device-scope counter) sums the 8
// partials for its 64 rows, adds bias, LeakyReLU, writes out — fused finish.
__global__ __launch_bounds__(256, 6) void dwt_mfma(const float* __restrict__ x,
                                                   const unsigned short* __restrict__ Wb,
                                                   float* __restrict__ partial,
                                                   int* __restrict__ counters,
                                                   const float* __restrict__ bias,
                                                   float* __restrict__ out, int B) {
    __shared__ __align__(16) unsigned short Wlds[KOUT * QCOLS];   // 16 KB
    __shared__ int s_last;
    const int t = threadIdx.x;
    const int rowgroup = blockIdx.x >> 3;
    const int kq = blockIdx.x & 7;

    // Stage: thread t loads row n = t&15, cols c0..c0+31 (64 B contiguous),
    // writes swizzled (short8-group XOR (n&7)*8) -> 2-way-max bank aliasing.
    {
        const int n = t & 15;
        const int c0 = (t >> 4) * 32;
        const unsigned short* src = Wb + n * INNER + kq * QCOLS + c0;
#pragma unroll
        for (int g = 0; g < 4; ++g) {
            const int c = c0 + g * 8;
            *(short8*)&Wlds[n * QCOLS + (c ^ ((n & 7) * 8))] = *(const short8*)(src + g * 8);
        }
    }
    __syncthreads();

    const int lane = t & 63;
    const int wid = t >> 6;
    const int qg = lane >> 4;         // K-subgroup 0..3
    const int mrow = lane & 15;       // M row within tile (A) == N col (B)
    const int rowbase = rowgroup * 64 + wid * 16;
    const float* xrow = x + (size_t)(rowbase + mrow) * INNER + kq * QCOLS;
    const unsigned short* wrow = &Wlds[mrow * QCOLS];
    const int swz = (mrow & 7) * 8;

    floatx4 acc = {0.f, 0.f, 0.f, 0.f};
#pragma unroll 4
    for (int step = 0; step < STEPS; ++step) {
        const int col = step * 32 + qg * 8;          // this lane's 8 K-elements
        const float4 lo = *(const float4*)(xrow + col);
        const float4 hi = *(const float4*)(xrow + col + 4);
        short8 a;
        a[0] = (short)bf16_rne(lo.x); a[1] = (short)bf16_rne(lo.y);
        a[2] = (short)bf16_rne(lo.z); a[3] = (short)bf16_rne(lo.w);
        a[4] = (short)bf16_rne(hi.x); a[5] = (short)bf16_rne(hi.y);
        a[6] = (short)bf16_rne(hi.z); a[7] = (short)bf16_rne(hi.w);
        const short8 b = *(const short8*)(wrow + (col ^ swz));
        acc = __builtin_amdgcn_mfma_f32_16x16x32_bf16(a, b, acc, 0, 0, 0);
    }

    // C mapping (m89-verified): col = lane&15 (= kout), row = (lane>>4)*4 + reg
    const int orow = rowbase + qg * 4;
    float* pq = partial + (size_t)kq * B * KOUT;
#pragma unroll
    for (int r = 0; r < 4; ++r)
        pq[(size_t)(orow + r) * KOUT + mrow] = acc[r];

    // ---- fused finish: last-arriving block of this rowgroup reduces partials ----
    __threadfence();                     // release this thread's partial stores (device scope)
    __syncthreads();                     // all threads of block have fenced
    if (t == 0) {
        int old = atomicAdd(&counters[rowgroup], 1);   // device-scope
        s_last = (old == KSPLIT - 1);
    }
    __syncthreads();
    if (!s_last) return;
    __threadfence();                     // acquire: other blocks' stores now visible

    // 64 rows x 16 k = 1024 outputs; thread t handles float4 at t*4.
    const size_t base = (size_t)rowgroup * 64 * KOUT + t * 4;
    const size_t stride = (size_t)B * KOUT;
    float4 s = *(const float4*)(partial + base);
#pragma unroll
    for (int q = 1; q < KSPLIT; ++q) {
        float4 p = *(const float4*)(partial + q * stride + base);
        s.x += p.x; s.y += p.y; s.z += p.z; s.w += p.w;
    }
    const float4 bb = *(const float4*)(bias + ((t * 4) & 15));
    s.x += bb.x; s.y += bb.y; s.z += bb.z; s.w += bb.w;
    s.x = (s.x >= 0.f) ? s.x : 1e-3f * s.x;
    s.y = (s.y >= 0.f) ? s.y : 1e-3f * s.y;
    s.z = (s.z >= 0.f) ? s.z : 1e-3f * s.z;
    s.w = (s.w >= 0.f) ? s.w : 1e-3f * s.w;
    *(float4*)(out + base) = s;
}

extern "C" void kernel_launch(void* const* d_in, const int* in_sizes, int n_in,
                              void* d_out, int out_size, void* d_ws, size_t ws_size,
                              hipStream_t stream) {
    const float* x      = (const float*)d_in[0];
    const float* conv_w = (const float*)d_in[1];
    const float* conv_b = (const float*)d_in[2];
    float* out = (float*)d_out;
    const int B = in_sizes[0] / INNER;   // 16384 (multiple of 64)
    const int ngroups = B / 64;          // 256

    float* partial = (float*)d_ws;                                              // 8 MB
    unsigned short* Wb = (unsigned short*)((char*)d_ws + ((size_t)16 << 20));   // 128 KB
    int* counters = (int*)((char*)d_ws + ((size_t)17 << 20));                   // 1 KB

    build_weff_bf16<<<(KOUT * INNER) / 256, 256, 0, stream>>>(conv_w, Wb, counters, ngroups);
    dwt_mfma<<<ngroups * KSPLIT, 256, 0, stream>>>(x, Wb, partial, counters, conv_b, out, B);
}

// Round 8
// 57.446 us; speedup vs baseline: 8.9689x; 8.9689x over previous
//
#include <hip/hip_runtime.h>
#include <hip/hip_bf16.h>

#define DWT_LEN_C 84
#define TDIM 64
#define INNER 4096   // 64 * 8 * 8
#define KOUT 16
#define KSPLIT 2
#define HCOLS 2048   // K-half width per block
#define OITER 16     // HCOLS / 128

typedef __attribute__((ext_vector_type(8))) short short8;
typedef __attribute__((ext_vector_type(4))) float floatx4;

__device__ __forceinline__ unsigned short bf16_rne(float f) {
    unsigned u = __float_as_uint(f);
    unsigned r = u + 0x7fffu + ((u >> 16) & 1u);
    return (unsigned short)(r >> 16);
}

// db4 analysis filters
__device__ const float c_dec_lo[8] = {-0.010597401784997278f, 0.032883011666982945f, 0.030841381835986965f,
                                      -0.18703481171888114f, -0.02798376941698385f, 0.6308807679295904f,
                                      0.7148465705525415f, 0.23037781330885523f};
__device__ const float c_dec_hi[8] = {-0.23037781330885523f, 0.7148465705525415f, -0.6308807679295904f,
                                      -0.02798376941698385f, 0.18703481171888114f, 0.030841381835986965f,
                                      -0.032883011666982945f, -0.010597401784997278f};

// Single-level analysis filter bank (reflect pad; left pad 6 for our sizes).
__device__ void afb1d_col(const float* v, int N, float* lo, float* hi, int M) {
    for (int i = 0; i < M; ++i) {
        float slo = 0.f, shi = 0.f;
        for (int j = 0; j < 8; ++j) {
            int idx = 2 * i + j - 6;
            if (idx < 0) idx = -idx;                  // reflect (exclude edge)
            if (idx >= N) idx = 2 * N - 2 - idx;
            float c = v[idx];
            slo = fmaf(c, c_dec_lo[7 - j], slo);      // conv = corr with reversed filter
            shi = fmaf(c, c_dec_hi[7 - j], shi);
        }
        lo[i] = slo; hi[i] = shi;
    }
}

// Fused setup: rebuild W_dwt[84][64] in LDS, emit W_eff bf16 [KOUT][INNER]
__global__ __launch_bounds__(256) void build_weff_bf16(const float* __restrict__ conv_w,
                                                       unsigned short* __restrict__ Wb) {
    __shared__ float Wd[DWT_LEN_C][TDIM];
    const int t0 = threadIdx.x;
    if (t0 < TDIM) {
        float v[64];
        for (int n = 0; n < 64; ++n) v[n] = (n == t0) ? 1.f : 0.f;
        float lo1[35], hi1[35], lo2[21], hi2[21], lo3[14], hi3[14];
        afb1d_col(v, 64, lo1, hi1, 35);
        afb1d_col(lo1, 35, lo2, hi2, 21);
        afb1d_col(lo2, 21, lo3, hi3, 14);
        for (int i = 0; i < 14; ++i) Wd[i][t0] = lo3[i];
        for (int i = 0; i < 35; ++i) Wd[14 + i][t0] = hi1[i];
        for (int i = 0; i < 21; ++i) Wd[49 + i][t0] = hi2[i];
        for (int i = 0; i < 14; ++i) Wd[70 + i][t0] = hi3[i];
    }
    __syncthreads();

    const int idx = blockIdx.x * 256 + threadIdx.x;    // k*4096 + col
    const int k = idx >> 12;
    const int col = idx & 4095;
    const int t = col >> 6;
    const int hw = col & 63;
    float s = 0.f;
    const float* cw = conv_w + (size_t)k * DWT_LEN_C * 64 + hw;
#pragma unroll 4
    for (int dd = 0; dd < DWT_LEN_C; ++dd)
        s = fmaf(cw[dd * 64], Wd[dd][t], s);
    Wb[idx] = bf16_rne(s);
}

// MFMA GEMM: M=B rows, N=16 outputs, K-half of 2048 cols per block (KSPLIT=2).
// Block: 256 thr / 4 waves, 64 rows (16 per wave). W half (16x2048 bf16 = 64 KB)
// staged once into LDS, XOR-swizzled for conflict-free ds_read_b128.
// Grid = 512 blocks = 2 blocks/CU (LDS-bound), 8 waves/CU.
// Explicit 2-stage register pipeline: load outer-iter j+1's x (8 float4/lane)
// while computing iter j's 4 MFMAs -> 8 KB in flight per wave.
__global__ __launch_bounds__(256) void dwt_mfma(const float* __restrict__ x,
                                                const unsigned short* __restrict__ Wb,
                                                float* __restrict__ partial, int B) {
    __shared__ __align__(16) unsigned short Wlds[KOUT * HCOLS];   // 64 KB
    const int t = threadIdx.x;
    const int rowgroup = blockIdx.x >> 1;
    const int kh = blockIdx.x & 1;

    // Stage: thread t loads row n = t&15, cols c0..c0+127 (256 B contiguous),
    // writes swizzled (short8-group XOR (n&7)*8) -> 2-way-max bank aliasing.
    {
        const int n = t & 15;
        const int c0 = (t >> 4) * 128;
        const unsigned short* src = Wb + n * INNER + kh * HCOLS + c0;
#pragma unroll
        for (int g = 0; g < 16; ++g) {
            const int c = c0 + g * 8;
            *(short8*)&Wlds[n * HCOLS + (c ^ ((n & 7) * 8))] = *(const short8*)(src + g * 8);
        }
    }
    __syncthreads();

    const int lane = t & 63;
    const int wid = t >> 6;
    const int qg = lane >> 4;         // K-subgroup 0..3
    const int mrow = lane & 15;       // M row within tile (A) == N col (B)
    const int rowbase = rowgroup * 64 + wid * 16;
    const float* xrow = x + (size_t)(rowbase + mrow) * INNER + kh * HCOLS + qg * 8;
    const unsigned short* wrow = &Wlds[mrow * HCOLS];
    const int swz = (mrow & 7) * 8;

    floatx4 acc = {0.f, 0.f, 0.f, 0.f};
    float4 bufA[8], bufB[8];

#define XLOAD(buf, it)                                                          \
    {                                                                           \
        const float* p = xrow + (it) * 128;                                     \
        _Pragma("unroll")                                                       \
        for (int s = 0; s < 4; ++s) {                                           \
            buf[2 * s]     = *(const float4*)(p + s * 32);                      \
            buf[2 * s + 1] = *(const float4*)(p + s * 32 + 4);                  \
        }                                                                       \
    }

#define XCOMPUTE(buf, it)                                                       \
    {                                                                           \
        _Pragma("unroll")                                                       \
        for (int s = 0; s < 4; ++s) {                                           \
            const float4 lo = buf[2 * s];                                       \
            const float4 hi = buf[2 * s + 1];                                   \
            short8 a;                                                           \
            a[0] = (short)bf16_rne(lo.x); a[1] = (short)bf16_rne(lo.y);         \
            a[2] = (short)bf16_rne(lo.z); a[3] = (short)bf16_rne(lo.w);         \
            a[4] = (short)bf16_rne(hi.x); a[5] = (short)bf16_rne(hi.y);         \
            a[6] = (short)bf16_rne(hi.z); a[7] = (short)bf16_rne(hi.w);         \
            const int col = (it) * 128 + s * 32 + qg * 8;                       \
            const short8 b = *(const short8*)(wrow + (col ^ swz));              \
            acc = __builtin_amdgcn_mfma_f32_16x16x32_bf16(a, b, acc, 0, 0, 0);  \
        }                                                                       \
    }

    XLOAD(bufA, 0);
#pragma unroll 1
    for (int it = 0; it < OITER; it += 2) {
        XLOAD(bufB, it + 1);
        XCOMPUTE(bufA, it);
        if (it + 2 < OITER) XLOAD(bufA, it + 2);
        XCOMPUTE(bufB, it + 1);
    }
#undef XLOAD
#undef XCOMPUTE

    // C mapping (m89-verified): col = lane&15 (= kout), row = (lane>>4)*4 + reg
    const int orow = rowbase + qg * 4;
    float* pq = partial + (size_t)kh * B * KOUT;
#pragma unroll
    for (int r = 0; r < 4; ++r)
        pq[(size_t)(orow + r) * KOUT + mrow] = acc[r];
}

// Sum KSPLIT partials + bias, LeakyReLU, write out. float4-vectorized.
__global__ __launch_bounds__(256) void finish(const float* __restrict__ partial,
                                              const float* __restrict__ bias,
                                              float* __restrict__ out, int B) {
    const int idx4 = (blockIdx.x * 256 + threadIdx.x) * 4;
    if (idx4 >= B * KOUT) return;
    const size_t stride = (size_t)B * KOUT;
    float4 s = *(const float4*)(partial + idx4);
#pragma unroll
    for (int q = 1; q < KSPLIT; ++q) {
        float4 p = *(const float4*)(partial + q * stride + idx4);
        s.x += p.x; s.y += p.y; s.z += p.z; s.w += p.w;
    }
    const float4 bb = *(const float4*)(bias + (idx4 & 15));
    s.x += bb.x; s.y += bb.y; s.z += bb.z; s.w += bb.w;
    s.x = (s.x >= 0.f) ? s.x : 1e-3f * s.x;
    s.y = (s.y >= 0.f) ? s.y : 1e-3f * s.y;
    s.z = (s.z >= 0.f) ? s.z : 1e-3f * s.z;
    s.w = (s.w >= 0.f) ? s.w : 1e-3f * s.w;
    *(float4*)(out + idx4) = s;
}

extern "C" void kernel_launch(void* const* d_in, const int* in_sizes, int n_in,
                              void* d_out, int out_size, void* d_ws, size_t ws_size,
                              hipStream_t stream) {
    const float* x      = (const float*)d_in[0];
    const float* conv_w = (const float*)d_in[1];
    const float* conv_b = (const float*)d_in[2];
    float* out = (float*)d_out;
    const int B = in_sizes[0] / INNER;   // 16384 (multiple of 64)

    float* partial = (float*)d_ws;                                             // 2 MB
    unsigned short* Wb = (unsigned short*)((char*)d_ws + ((size_t)4 << 20));   // 128 KB

    build_weff_bf16<<<(KOUT * INNER) / 256, 256, 0, stream>>>(conv_w, Wb);
    dwt_mfma<<<(B / 64) * KSPLIT, 256, 0, stream>>>(x, Wb, partial, B);
    finish<<<(B * KOUT / 4 + 255) / 256, 256, 0, stream>>>(partial, conv_b, out, B);
}